// Round 5
// baseline (514.071 us; speedup 1.0000x reference)
//
#include <hip/hip_runtime.h>
#include <hip/hip_bf16.h>
#include <math.h>
#include <stdint.h>

// Problem constants (from setup_inputs)
#define B_ 32
#define T_ 512
#define D_ 1024
#define N_ 50000
#define S_ 4096

// 1 / log(N+1) = 1 / log(50001)
#define INV_LOG_NP1 0.09242317f

// W is pre-scaled by 64 when converting to fp8 e4m3 (raw W*0.02 lands in the
// subnormal zone); the GEMM accumulator is multiplied by 1/64 in the epilogue.
#define WSCALE 64.0f
#define INV_WSCALE 0.015625f
#define LOG2E 1.4426950408889634f

typedef __attribute__((ext_vector_type(8))) short bf16x8;   // bf16 MFMA A/B frag
typedef __attribute__((ext_vector_type(4))) float f32x4;    // MFMA C/D frag
typedef __attribute__((ext_vector_type(4))) short s16x4;    // 8B store

// fp32 -> bf16 round-to-nearest-even (fallback path)
__device__ __forceinline__ short f2bf(float f) {
    unsigned u = __float_as_uint(f);
    u += 0x7fffu + ((u >> 16) & 1u);
    return (short)(u >> 16);
}

// pack 4 floats -> 4 fp8 e4m3 bytes (HW cvt, OCP format on gfx950)
__device__ __forceinline__ int pack_fp8x4(float a, float b, float c, float d) {
    int v = __builtin_amdgcn_cvt_pk_fp8_f32(a, b, 0, false);   // bytes 0,1
    v = __builtin_amdgcn_cvt_pk_fp8_f32(c, d, v, true);        // bytes 2,3
    return v;
}

// log E[count] for log-uniform unique sampling (TF formula), fp32 like the ref
__device__ __forceinline__ float log_expected(int id) {
    float p  = log1pf(1.0f / ((float)id + 1.0f)) * INV_LOG_NP1;  // P(c)
    return logf(-expm1f((float)S_ * log1pf(-p)));                // log(1-(1-p)^S)
}

// async global->LDS, 16 B per lane; LDS dest = wave-uniform base + lane*16
__device__ __forceinline__ void gload_lds16(const void* g, void* l) {
    __builtin_amdgcn_global_load_lds(
        (const __attribute__((address_space(1))) void*)g,
        (__attribute__((address_space(3))) void*)l, 16, 0, 0);
}

// ---------------------------------------------------------------------------
// Kernel P (fast path): fused {W fp32 -> fp8 table} + {true logits + x -> fp8}.
// Blocks [0, NCVT) convert W (each thread 8 elems, exactly covers N*D).
// Blocks [NCVT, NCVT + B*T/4) compute true logits, one wave per token, and
// emit x in fp8 (x is being read here anyway).
__global__ __launch_bounds__(256) void prep_kernel(
    const float* __restrict__ x, const float* __restrict__ W,
    const float* __restrict__ bvec, const int* __restrict__ labels,
    float* __restrict__ true_logit, float* __restrict__ denom,
    unsigned char* __restrict__ xf8, unsigned char* __restrict__ Wf8)
{
    constexpr int NCVT = N_ * D_ / 2048;        // 25000
    if (blockIdx.x < NCVT) {
        size_t i = ((size_t)blockIdx.x * 2048) + (size_t)threadIdx.x * 8;
        float4 a = *(const float4*)(W + i);
        float4 b = *(const float4*)(W + i + 4);
        int2 o;
        o.x = pack_fp8x4(a.x * WSCALE, a.y * WSCALE, a.z * WSCALE, a.w * WSCALE);
        o.y = pack_fp8x4(b.x * WSCALE, b.y * WSCALE, b.z * WSCALE, b.w * WSCALE);
        *(int2*)(Wf8 + i) = o;
        return;
    }
    int w = threadIdx.x >> 6, lane = threadIdx.x & 63;
    int token = (blockIdx.x - NCVT) * 4 + w;    // B*T/4 blocks, exact
    int lab = labels[token];
    const float4* xp = (const float4*)(x + (size_t)token * D_);
    const float4* wp = (const float4*)(W + (size_t)lab * D_);
    float acc = 0.0f;
#pragma unroll
    for (int j = 0; j < 4; ++j) {               // 1024 floats = 256 float4 / 64 lanes
        float4 a = xp[lane + 64 * j];
        float4 c = wp[lane + 64 * j];
        acc += a.x * c.x + a.y * c.y + a.z * c.z + a.w * c.w;
        int o = pack_fp8x4(a.x, a.y, a.z, a.w);
        *(int*)(xf8 + (size_t)token * D_ + (lane + 64 * j) * 4) = o;
    }
#pragma unroll
    for (int m = 32; m >= 1; m >>= 1) acc += __shfl_xor(acc, m);
    if (lane == 0) {
        float tl = acc + bvec[lab] - log_expected(lab);
        true_logit[token] = tl;
        denom[token] = __expf(tl);
    }
}

// ---------------------------------------------------------------------------
// Kernel 1 (FALLBACK): true logits only (no fp8 emit).
__global__ __launch_bounds__(256) void true_logit_kernel(
    const float* __restrict__ x, const float* __restrict__ W,
    const float* __restrict__ bvec, const int* __restrict__ labels,
    float* __restrict__ true_logit, float* __restrict__ denom)
{
    int w = threadIdx.x >> 6, lane = threadIdx.x & 63;
    int token = blockIdx.x * 4 + w;             // grid = B*T/4, exact
    int lab = labels[token];
    const float4* xp = (const float4*)(x + (size_t)token * D_);
    const float4* wp = (const float4*)(W + (size_t)lab * D_);
    float acc = 0.0f;
#pragma unroll
    for (int j = 0; j < 4; ++j) {
        float4 a = xp[lane + 64 * j];
        float4 c = wp[lane + 64 * j];
        acc += a.x * c.x + a.y * c.y + a.z * c.z + a.w * c.w;
    }
#pragma unroll
    for (int m = 32; m >= 1; m >>= 1) acc += __shfl_xor(acc, m);
    if (lane == 0) {
        float tl = acc + bvec[lab] - log_expected(lab);
        true_logit[token] = tl;
        denom[token] = __expf(tl);
    }
}

// ---------------------------------------------------------------------------
// Kernel 2 (FAST): fused sampled-logits GEMM + exp-sum epilogue, fp8 e4m3,
// 256x256 tile, BK=128 bytes, DOUBLE-BUFFERED LDS with COUNTED vmcnt (T3/T4):
// the main loop never drains vmcnt to 0 — prefetch loads stay in flight
// across barriers, covered by a full K-tile of MFMA compute.
//
// Schedule per K-tile t (8 tiles total, buffers alternate t&1):
//   compute(buf[t&1])                      // 4 kstep-pairs, 128 MFMA/wave
//   s_barrier                              // all readers of buf[t&1] done
//   STAGE(tile t+2 -> buf[t&1])            // 8 gload_lds16/thread
//   s_waitcnt vmcnt(8)                     // own tile-(t+1) loads retired
//   s_barrier                              // tile t+1 visible to all waves
// Raw __builtin_amdgcn_s_barrier + asm waitcnt ("memory" clobber) because
// __syncthreads() would emit vmcnt(0) and drain the pipeline (the m97 stall).
// sched_barrier(0) after each waitcnt (guide rule #18).
//
// K-PERMUTATION TRICK (unchanged from the verified 128^2 kernel — rows are
// 128 B in both): MFMA kstep t, lane quad lq consumes global k = lq*32+t*8..;
// a kstep-pair's data = one staged 16-B chunk -> conflict-free ds_read_b128.
// LDS row = 8 chunks of 16 B; chunk c of row r at slot c^(r&7); staging lane
// l loads chunk (l&7)^(l>>3) of row seg*8+(l>>3), seg = 4*w + j (w=0..7).
//
// Register discipline: acc[8][4] f32x4 -> 128 AGPRs (same intrinsic as the
// verified round-0 kernel, which AGPR-allocates); B frags 16 VGPR, A frags
// streamed one long2 at a time.  __launch_bounds__(512,2) caps combined
// VGPR+AGPR at 256/wave (2 waves/SIMD).
__global__ __launch_bounds__(512, 2) void sampled_gemm_fp8_256(
    const unsigned char* __restrict__ xf8, const unsigned char* __restrict__ Wf8,
    const float* __restrict__ bvec, const int* __restrict__ labels,
    const int* __restrict__ sampled, float* __restrict__ denom)
{
    constexpr int BM2 = 256, BN2 = 256, BK2 = 128;
    constexpr int TILE = BM2 * BK2;                 // 32 KB per buffer side
    __shared__ __align__(16) unsigned char At[2][TILE];   // 64 KB
    __shared__ __align__(16) unsigned char Bt[2][TILE];   // 64 KB
    __shared__ float colbias[BN2];    // (b - logE) * log2(e)
    __shared__ int   ids[BN2];
    __shared__ int   labT[BM2];

    int bidx = blockIdx.x;            // grid = B * (T/256) * (S/256) = 32*2*16
    int b    = bidx >> 5;
    int rem  = bidx & 31;
    int mT   = rem >> 4;              // 0..1
    int nT   = rem & 15;              // 0..15

    int tid  = threadIdx.x;           // 0..511, 8 waves
    int w    = tid >> 6, lane = tid & 63;

    // ---- staging geometry: 8 KB per issue = 64 lanes x (8 rows x 128 B)/8 ----
    int r = lane >> 3;                       // 0..7 row within 8-row segment
    int s = lane & 7;                        // LDS slot (16 B units)
    int c = s ^ r;                           // global chunk this lane loads

    int tokBase = b * T_ + mT * BM2;
    const unsigned char* gA[4];
    const unsigned char* gB[4];
    int lOff[4];
#pragma unroll
    for (int j = 0; j < 4; ++j) {
        int seg = 4 * w + j;                 // 0..31: wave w stages segs 4w..4w+3
        int row = seg * 8 + r;               // 0..255
        gA[j] = xf8 + (size_t)(tokBase + row) * D_ + c * 16;
        int id = sampled[b * S_ + nT * BN2 + row];
        gB[j] = Wf8 + (size_t)id * D_ + c * 16;
        lOff[j] = seg * 1024;                // 1 KB per segment
    }

#define STAGE(buf)                                                            \
    do {                                                                      \
        _Pragma("unroll")                                                     \
        for (int j = 0; j < 4; ++j) { gload_lds16(gA[j], At[buf] + lOff[j]); gA[j] += BK2; } \
        _Pragma("unroll")                                                     \
        for (int j = 0; j < 4; ++j) { gload_lds16(gB[j], Bt[buf] + lOff[j]); gB[j] += BK2; } \
    } while (0)

    // ---- prologue: stage tiles 0 and 1; metadata overlaps the loads ----
    STAGE(0);
    if (tid < BN2) {
        int id = sampled[b * S_ + nT * BN2 + tid];
        ids[tid] = id;
        colbias[tid] = (bvec[id] - log_expected(id)) * LOG2E;
    } else {
        int i = tid - BN2;
        labT[i] = labels[b * T_ + mT * BM2 + i];
    }
    STAGE(1);
    // tile 0 resident (own 8 oldest of 16+ vm ops) + metadata ds_writes drained
    asm volatile("s_waitcnt vmcnt(8) lgkmcnt(0)" ::: "memory");
    __builtin_amdgcn_sched_barrier(0);
    __builtin_amdgcn_s_barrier();
    asm volatile("" ::: "memory");

    f32x4 acc[8][4];
#pragma unroll
    for (int mi = 0; mi < 8; ++mi)
#pragma unroll
        for (int ni = 0; ni < 4; ++ni) acc[mi][ni] = (f32x4){0.f, 0.f, 0.f, 0.f};

    int waveM = w >> 2, waveN = w & 3;       // 2 x 4 wave grid
    int lr = lane & 15, lq = lane >> 4;
    int aRow[8], bRow[4];
#pragma unroll
    for (int i = 0; i < 8; ++i) aRow[i] = (waveM * 128 + i * 16 + lr) * BK2;
#pragma unroll
    for (int i = 0; i < 4; ++i) bRow[i] = (waveN * 64 + i * 16 + lr) * BK2;
    int offP[2];
#pragma unroll
    for (int tp = 0; tp < 2; ++tp)
        offP[tp] = ((2 * lq + tp) ^ (lr & 7)) * 16;

    for (int t = 0; t < 8; ++t) {
        const unsigned char* Ac = At[t & 1];
        const unsigned char* Bc = Bt[t & 1];
#pragma unroll
        for (int tp = 0; tp < 2; ++tp) {      // two kstep-pairs per BK tile
            long2 bv[4];
#pragma unroll
            for (int ni = 0; ni < 4; ++ni)
                bv[ni] = *(const long2*)(Bc + bRow[ni] + offP[tp]);
#pragma unroll
            for (int mi = 0; mi < 8; ++mi) {  // A streamed: one long2 live
                long2 av = *(const long2*)(Ac + aRow[mi] + offP[tp]);
#pragma unroll
                for (int ni = 0; ni < 4; ++ni)
                    acc[mi][ni] = __builtin_amdgcn_mfma_f32_16x16x32_fp8_fp8(
                        av.x, bv[ni].x, acc[mi][ni], 0, 0, 0);
#pragma unroll
                for (int ni = 0; ni < 4; ++ni)
                    acc[mi][ni] = __builtin_amdgcn_mfma_f32_16x16x32_fp8_fp8(
                        av.y, bv[ni].y, acc[mi][ni], 0, 0, 0);
            }
        }
        if (t == 7) break;
        // readers of buf[t&1] done -> safe to overwrite with tile t+2
        asm volatile("" ::: "memory");
        __builtin_amdgcn_s_barrier();
        asm volatile("" ::: "memory");
        if (t < 6) {
            STAGE(t & 1);                     // tile t+2 into freed buffer
            asm volatile("s_waitcnt vmcnt(8)" ::: "memory");   // t+1 retired
        } else {
            asm volatile("s_waitcnt vmcnt(0)" ::: "memory");   // tail drain (t=6)
        }
        __builtin_amdgcn_sched_barrier(0);
        __builtin_amdgcn_s_barrier();         // tile t+1 visible to all waves
        asm volatile("" ::: "memory");
    }
#undef STAGE

    // Epilogue: exp2-domain (acc and bias pre-scaled by log2e), accidental-hit
    // mask, row-sum, atomicAdd.
    // C/D layout (verified m89/m91): col = lane&15, row = (lane>>4)*4 + reg
    const float accScale = INV_WSCALE * LOG2E;
    float* dptr = denom + b * T_ + mT * BM2;
#pragma unroll
    for (int mi = 0; mi < 8; ++mi) {
#pragma unroll
        for (int rr = 0; rr < 4; ++rr) {
            int localRow = waveM * 128 + mi * 16 + lq * 4 + rr;
            int lab = labT[localRow];
            float sum = 0.0f;
#pragma unroll
            for (int ni = 0; ni < 4; ++ni) {
                int col = waveN * 64 + ni * 16 + lr;
                float v = acc[mi][ni][rr] * accScale + colbias[col];
                sum += (ids[col] == lab) ? 0.0f : exp2f(v);
            }
            sum += __shfl_xor(sum, 1);
            sum += __shfl_xor(sum, 2);
            sum += __shfl_xor(sum, 4);
            sum += __shfl_xor(sum, 8);
            if (lr == 0) atomicAdd(&dptr[localRow], sum);
        }
    }
}

constexpr int BM = 128, BN = 128;

// ---------------------------------------------------------------------------
// Kernel 2 (FALLBACK): register-staging fp32->bf16 GEMM (small-ws path).
__global__ __launch_bounds__(256) void sampled_gemm(
    const float* __restrict__ x, const float* __restrict__ W,
    const float* __restrict__ bvec, const int* __restrict__ labels,
    const int* __restrict__ sampled, float* __restrict__ denom)
{
    constexpr int FBK = 32;
    __shared__ short At[BM * FBK];
    __shared__ short Bt[BN * FBK];
    __shared__ float colbias[BN];
    __shared__ int   ids[BN];
    __shared__ int   labT[BM];

    int bidx = blockIdx.x;
    int b    = bidx >> 7;
    int rem  = bidx & 127;
    int mT   = rem >> 5;
    int nT   = rem & 31;
    int tid = threadIdx.x;

    if (tid < BN) {
        int id = sampled[b * S_ + nT * BN + tid];
        ids[tid] = id;
        colbias[tid] = bvec[id] - log_expected(id);
    } else {
        int i = tid - BN;
        labT[i] = labels[b * T_ + mT * BM + i];
    }
    __syncthreads();

    const float* asrc[4];
    const float* bsrc[4];
    int ch = tid & 7;
#pragma unroll
    for (int j = 0; j < 4; ++j) {
        int row = (tid >> 3) + 32 * j;
        asrc[j] = x + ((size_t)(b * T_ + mT * BM + row)) * D_ + ch * 4;
        bsrc[j] = W + (size_t)ids[row] * D_ + ch * 4;
    }

    f32x4 acc[4][4];
#pragma unroll
    for (int mi = 0; mi < 4; ++mi)
#pragma unroll
        for (int ni = 0; ni < 4; ++ni) acc[mi][ni] = (f32x4){0.f, 0.f, 0.f, 0.f};

    int w = tid >> 6, lane = tid & 63;
    int waveM = w >> 1, waveN = w & 1;
    int lr = lane & 15, lq = lane >> 4;

    for (int k0 = 0; k0 < D_; k0 += FBK) {
        __syncthreads();
#pragma unroll
        for (int j = 0; j < 4; ++j) {
            int row = (tid >> 3) + 32 * j;
            float4 va = *(const float4*)(asrc[j] + k0);
            s16x4 pa = {f2bf(va.x), f2bf(va.y), f2bf(va.z), f2bf(va.w)};
            *(s16x4*)&At[row * FBK + ch * 4] = pa;
            float4 vb = *(const float4*)(bsrc[j] + k0);
            s16x4 pb = {f2bf(vb.x), f2bf(vb.y), f2bf(vb.z), f2bf(vb.w)};
            *(s16x4*)&Bt[row * FBK + ch * 4] = pb;
        }
        __syncthreads();
        bf16x8 af[4], bfr[4];
#pragma unroll
        for (int mi = 0; mi < 4; ++mi)
            af[mi] = *(const bf16x8*)&At[(waveM * 64 + mi * 16 + lr) * FBK + lq * 8];
#pragma unroll
        for (int ni = 0; ni < 4; ++ni)
            bfr[ni] = *(const bf16x8*)&Bt[(waveN * 64 + ni * 16 + lr) * FBK + lq * 8];
#pragma unroll
        for (int mi = 0; mi < 4; ++mi)
#pragma unroll
            for (int ni = 0; ni < 4; ++ni)
                acc[mi][ni] = __builtin_amdgcn_mfma_f32_16x16x32_bf16(
                    af[mi], bfr[ni], acc[mi][ni], 0, 0, 0);
    }

    float* dptr = denom + b * T_ + mT * BM;
#pragma unroll
    for (int mi = 0; mi < 4; ++mi) {
#pragma unroll
        for (int rr = 0; rr < 4; ++rr) {
            int localRow = waveM * 64 + mi * 16 + lq * 4 + rr;
            int lab = labT[localRow];
            float sum = 0.0f;
#pragma unroll
            for (int ni = 0; ni < 4; ++ni) {
                int col = waveN * 64 + ni * 16 + lr;
                float v = acc[mi][ni][rr] + colbias[col];
                sum += (ids[col] == lab) ? 0.0f : __expf(v);
            }
            sum += __shfl_xor(sum, 1);
            sum += __shfl_xor(sum, 2);
            sum += __shfl_xor(sum, 4);
            sum += __shfl_xor(sum, 8);
            if (lr == 0) atomicAdd(&dptr[localRow], sum);
        }
    }
}

// ---------------------------------------------------------------------------
// Kernel 3: token_loss = log(denom) - true_logit; out = 0.5 * mean
__global__ __launch_bounds__(256) void finalize_kernel(
    const float* __restrict__ true_logit, const float* __restrict__ denom,
    float* __restrict__ out)
{
    float s = 0.0f;
    for (int i = threadIdx.x; i < B_ * T_; i += 256)
        s += __logf(denom[i]) - true_logit[i];
#pragma unroll
    for (int m = 32; m >= 1; m >>= 1) s += __shfl_xor(s, m);
    __shared__ float wsum[4];
    if ((threadIdx.x & 63) == 0) wsum[threadIdx.x >> 6] = s;
    __syncthreads();
    if (threadIdx.x == 0)
        out[0] = 0.5f * (wsum[0] + wsum[1] + wsum[2] + wsum[3]) / (float)(B_ * T_);
}

// ---------------------------------------------------------------------------
extern "C" void kernel_launch(void* const* d_in, const int* in_sizes, int n_in,
                              void* d_out, int out_size, void* d_ws, size_t ws_size,
                              hipStream_t stream) {
    const float* x       = (const float*)d_in[0];   // [B,T,D]
    const float* W       = (const float*)d_in[1];   // [N,D]
    const float* bvec    = (const float*)d_in[2];   // [N]
    const int*   labels  = (const int*)d_in[3];     // [B,T]
    const int*   sampled = (const int*)d_in[4];     // [B,S]
    float* out = (float*)d_out;

    float* true_logit   = (float*)d_ws;                 // B*T floats
    float* denom        = true_logit + B_ * T_;         // B*T floats
    unsigned char* xf8  = (unsigned char*)(denom + B_ * T_);  // B*T*D fp8 (16.8 MB)
    unsigned char* Wf8  = xf8 + (size_t)B_ * T_ * D_;   // N*D fp8 (51.2 MB)

    const size_t NEED = (size_t)2 * B_ * T_ * 4
                      + (size_t)B_ * T_ * D_
                      + (size_t)N_ * D_;               // ~68.2 MB

    if (ws_size >= NEED) {
        prep_kernel<<<N_ * D_ / 2048 + B_ * T_ / 4, 256, 0, stream>>>(
            x, W, bvec, labels, true_logit, denom, xf8, Wf8);
        sampled_gemm_fp8_256<<<B_ * (T_ / 256) * (S_ / 256), 512, 0, stream>>>(
            xf8, Wf8, bvec, labels, sampled, denom);
    } else {
        true_logit_kernel<<<B_ * T_ / 4, 256, 0, stream>>>(
            x, W, bvec, labels, true_logit, denom);
        sampled_gemm<<<B_ * (T_ / BM) * (S_ / BN), 256, 0, stream>>>(
            x, W, bvec, labels, sampled, denom);
    }
    finalize_kernel<<<1, 256, 0, stream>>>(true_logit, denom, out);
}